// Round 1
// baseline (517.199 us; speedup 1.0000x reference)
//
#include <hip/hip_runtime.h>

#define NN 512
#define NP (NN*NN)      // 262144 pairs
// D = H = 64, O0 = O1 = 32

typedef __bf16 bf16x8 __attribute__((ext_vector_type(8)));
typedef float  f32x4  __attribute__((ext_vector_type(4)));

// Radial schedule: {x-select, weight-select, is-vector-output}
//  rd0: radial(x0,f0)  -> out0_a   rd1: radial(x1,f0)  -> out0_b
//  rd2: filter1(x0,f11)-> out1_a   rd3: filter1(x1,f10)-> out1_b
//  rd4: filter1(x1,f11)-> out1_c

__global__ __launch_bounds__(256) void conv_fused_kernel(
    const float* __restrict__ x0, const float* __restrict__ x1,
    const float* __restrict__ rij,
    const float* __restrict__ w1_0, const float* __restrict__ b1_0,
    const float* __restrict__ w2_0, const float* __restrict__ b2_0,
    const float* __restrict__ w1_1, const float* __restrict__ b1_1,
    const float* __restrict__ w2_1, const float* __restrict__ b2_1,
    const float* __restrict__ w1_2, const float* __restrict__ b1_2,
    const float* __restrict__ w2_2, const float* __restrict__ b2_2,
    float* __restrict__ out)
{
    // Weights transposed (so B-frags are 8 contiguous k per lane -> ds_read_b128),
    // rows padded to 72 elems (144 B, 16B-divisible so vector reads stay aligned).
    __shared__ __attribute__((aligned(16))) __bf16 sW1T[3][64][72]; // [w][dh][din]
    __shared__ __attribute__((aligned(16))) __bf16 sW2T[3][32][72]; // [w][dout][dh]
    __shared__ float sB1[3][64];
    __shared__ float sB2[3][32];
    __shared__ __attribute__((aligned(16))) __bf16 sH[4][16][72];   // per-wave H round-trip
    __shared__ float sU[4][16][4];                                  // per-wave unit vectors

    const int tid = threadIdx.x;
    const int wv  = tid >> 6;   // wave id 0..3
    const int ln  = tid & 63;   // lane
    const int l16 = ln & 15;
    const int q   = ln >> 4;    // quad 0..3

    // ---- stage weights (once per block; reads are L2/L3 hits across blocks) ----
    {
        const float* w1s[3] = {w1_0, w1_1, w1_2};
        const float* w2s[3] = {w2_0, w2_1, w2_2};
        const float* b1s[3] = {b1_0, b1_1, b1_2};
        const float* b2s[3] = {b2_0, b2_1, b2_2};
        for (int w = 0; w < 3; ++w) {
            for (int e = tid; e < 64*64; e += 256) {
                int k = e >> 6, n = e & 63;              // w1 is [din][dh] row-major
                sW1T[w][n][k] = (__bf16)w1s[w][e];
            }
            for (int e = tid; e < 64*32; e += 256) {
                int k = e >> 5, n = e & 31;              // w2 is [dh][dout]
                sW2T[w][n][k] = (__bf16)w2s[w][e];
            }
            if (tid < 64) sB1[w][tid] = b1s[w][tid];
            if (tid < 32) sB2[w][tid] = b2s[w][tid];
        }
    }
    __syncthreads();

    const size_t OB0a = 0;
    const size_t OB0b = (size_t)NP * 32;
    const size_t OB1a = (size_t)NP * 64;
    const size_t OB1b = OB1a + (size_t)NP * 96;
    const size_t OB1c = OB1b + (size_t)NP * 96;

    const int xsel[5]    = {0, 1, 0, 1, 1};
    const int wsel[5]    = {0, 0, 2, 1, 2};
    const size_t obase[5] = {OB0a, OB0b, OB1a, OB1b, OB1c};

    // 4 m-tiles of 16 pairs per wave -> 256 pairs per block
    for (int t = 0; t < 4; ++t) {
        const int p0 = blockIdx.x * 256 + (t * 4 + wv) * 16;

        // unit vectors (mask for dij<EPS folded in): lanes 0..15, one row each
        if (ln < 16) {
            const float* rp = rij + (size_t)(p0 + ln) * 3;
            float r0 = rp[0], r1 = rp[1], r2 = rp[2];
            float s  = r0*r0 + r1*r1 + r2*r2;
            float inv = (s < 1e-16f) ? 0.0f : (1.0f / sqrtf(fmaxf(s, 1e-8f)));
            sU[wv][ln][0] = r0 * inv;
            sU[wv][ln][1] = r1 * inv;
            sU[wv][ln][2] = r2 * inv;
        }

        // A-fragments for x0 and x1 (reused across radials)
        // lane holds X[p0 + l16][ks*32 + q*8 + j], j=0..7
        bf16x8 ax[2][2];
        {
            const float* xs[2] = {x0, x1};
            #pragma unroll
            for (int xi = 0; xi < 2; ++xi) {
                const float* xr = xs[xi] + (size_t)(p0 + l16) * 64 + q * 8;
                #pragma unroll
                for (int ks = 0; ks < 2; ++ks) {
                    float4 v0 = *(const float4*)(xr + ks * 32);
                    float4 v1 = *(const float4*)(xr + ks * 32 + 4);
                    bf16x8 a;
                    a[0] = (__bf16)v0.x; a[1] = (__bf16)v0.y;
                    a[2] = (__bf16)v0.z; a[3] = (__bf16)v0.w;
                    a[4] = (__bf16)v1.x; a[5] = (__bf16)v1.y;
                    a[6] = (__bf16)v1.z; a[7] = (__bf16)v1.w;
                    ax[xi][ks] = a;
                }
            }
        }

        // sU visible to whole wave (same-wave DS is in-order; fence stops compiler reorder)
        asm volatile("s_waitcnt lgkmcnt(0)" ::: "memory");

        for (int rd = 0; rd < 5; ++rd) {
            const int w = wsel[rd];

            // ---- GEMM1: H = relu(X @ W1 + b1), 16x64 ----
            f32x4 acc[4];
            #pragma unroll
            for (int nt = 0; nt < 4; ++nt) acc[nt] = (f32x4){0.f, 0.f, 0.f, 0.f};
            #pragma unroll
            for (int nt = 0; nt < 4; ++nt) {
                #pragma unroll
                for (int ks = 0; ks < 2; ++ks) {
                    bf16x8 b = *(const bf16x8*)&sW1T[w][nt * 16 + l16][ks * 32 + q * 8];
                    acc[nt] = __builtin_amdgcn_mfma_f32_16x16x32_bf16(
                        ax[xsel[rd]][ks], b, acc[nt], 0, 0, 0);
                }
            }
            // bias + relu, write H to LDS in row-major (C-layout -> memory)
            #pragma unroll
            for (int nt = 0; nt < 4; ++nt) {
                float bb = sB1[w][nt * 16 + l16];
                #pragma unroll
                for (int r = 0; r < 4; ++r) {
                    float h = fmaxf(acc[nt][r] + bb, 0.0f);
                    sH[wv][q * 4 + r][nt * 16 + l16] = (__bf16)h;
                }
            }
            asm volatile("s_waitcnt lgkmcnt(0)" ::: "memory");

            // H back as A-fragments
            bf16x8 h2[2];
            h2[0] = *(const bf16x8*)&sH[wv][l16][q * 8];
            h2[1] = *(const bf16x8*)&sH[wv][l16][32 + q * 8];

            // ---- GEMM2: RAD = H @ W2 + b2, 16x32 ----
            f32x4 acc2[2];
            acc2[0] = (f32x4){0.f, 0.f, 0.f, 0.f};
            acc2[1] = (f32x4){0.f, 0.f, 0.f, 0.f};
            #pragma unroll
            for (int nt = 0; nt < 2; ++nt) {
                #pragma unroll
                for (int ks = 0; ks < 2; ++ks) {
                    bf16x8 b = *(const bf16x8*)&sW2T[w][nt * 16 + l16][ks * 32 + q * 8];
                    acc2[nt] = __builtin_amdgcn_mfma_f32_16x16x32_bf16(
                        h2[ks], b, acc2[nt], 0, 0, 0);
                }
            }

            // ---- epilogue ----
            if (rd < 2) {
                // out0: [p][o]
                #pragma unroll
                for (int nt = 0; nt < 2; ++nt) {
                    float bb = sB2[w][nt * 16 + l16];
                    #pragma unroll
                    for (int r = 0; r < 4; ++r) {
                        int p = p0 + q * 4 + r;
                        out[obase[rd] + (size_t)p * 32 + nt * 16 + l16] = acc2[nt][r] + bb;
                    }
                }
            } else {
                // out1: [p][o][3] = u[p][c] * rad[p][o]
                #pragma unroll
                for (int nt = 0; nt < 2; ++nt) {
                    float bb = sB2[w][nt * 16 + l16];
                    #pragma unroll
                    for (int r = 0; r < 4; ++r) {
                        int pr = q * 4 + r;
                        int p  = p0 + pr;
                        float rv = acc2[nt][r] + bb;
                        size_t base = obase[rd] + ((size_t)p * 32 + nt * 16 + l16) * 3;
                        out[base + 0] = rv * sU[wv][pr][0];
                        out[base + 1] = rv * sU[wv][pr][1];
                        out[base + 2] = rv * sU[wv][pr][2];
                    }
                }
            }
            // next radial's sH writes are issued after this radial's sH reads:
            // same-wave DS pipe is in-order, asm fences prevent compiler reordering.
        }
    }
}

extern "C" void kernel_launch(void* const* d_in, const int* in_sizes, int n_in,
                              void* d_out, int out_size, void* d_ws, size_t ws_size,
                              hipStream_t stream) {
    const float* x0   = (const float*)d_in[0];
    const float* x1   = (const float*)d_in[1];
    // d_in[2] = rbf : unused by the reference
    const float* rij  = (const float*)d_in[3];

    conv_fused_kernel<<<NP / 256, 256, 0, stream>>>(
        x0, x1, rij,
        (const float*)d_in[4],  (const float*)d_in[5],  (const float*)d_in[6],  (const float*)d_in[7],   // f0
        (const float*)d_in[8],  (const float*)d_in[9],  (const float*)d_in[10], (const float*)d_in[11],  // f10
        (const float*)d_in[12], (const float*)d_in[13], (const float*)d_in[14], (const float*)d_in[15],  // f11
        (float*)d_out);
}